// Round 4
// baseline (106.187 us; speedup 1.0000x reference)
//
#include <hip/hip_runtime.h>
#include <hip/hip_fp16.h>

// Coulomb pair-energy reduction via 2D pair bucketing + LDS-staged QUANTIZED
// atom tiles (8B records: u16 fractional x,y,z + f16 charge).
// inputs: 0 coords f32[100000*3], 1 pairs i32[6400000*2], 2 box f32[9],
//         3 charges f32[100000], 4 prefac f32[1], 5 cutoff f32[1], 6 do_shift i32[1]
// output: f32[1] = prefac * sum_masked(q_i q_j (1/r - shift))
//
// R3: scatter write-amplification fix (169 buckets instead of 625, runs ~390B),
// 8B records so both 8192-atom tiles fit in 128KB LDS, integer PBC wrap.

constexpr int TPB = 256;

constexpr int CHUNK_SHIFT = 13;
constexpr int CHUNK       = 1 << CHUNK_SHIFT;   // 8192 atoms/chunk
constexpr int NCHUNK_MAX  = 16;
constexpr int NBUCKET_MAX = NCHUNK_MAX * NCHUNK_MAX;
constexpr int CAP         = 44032;              // max bucket mean 42950 + 5 sigma
constexpr int OV_CAP      = 131072;

// ws layout (bytes)
constexpr size_t WS_ACC    = 0;         // double
constexpr size_t WS_PAR    = 16;        // float[24]
constexpr size_t WS_GCOUNT = 256;       // u32[NBUCKET_MAX]
constexpr size_t WS_OVCNT  = 1536;      // u32
constexpr size_t WS_OVLIST = 2048;      // int2[OV_CAP] ~1MB
constexpr size_t WS_QATOMS = 2u << 20;  // uint2[natoms]
constexpr size_t WS_BUCKET = 4u << 20;  // u32[nbucket*CAP]

// par: [0..8] boxInv, [9] cutoff^2, [10] shift, [11..19] box/65536
__global__ void setup_kernel(const float* __restrict__ box,
                             const float* __restrict__ cutoff_p,
                             const int* __restrict__ do_shift_p,
                             double* __restrict__ acc,
                             float* __restrict__ par) {
    if (threadIdx.x == 0 && blockIdx.x == 0) {
        *acc = 0.0;
        float b00 = box[0], b01 = box[1], b02 = box[2];
        float b10 = box[3], b11 = box[4], b12 = box[5];
        float b20 = box[6], b21 = box[7], b22 = box[8];
        float det = b00*(b11*b22 - b12*b21)
                  - b01*(b10*b22 - b12*b20)
                  + b02*(b10*b21 - b11*b20);
        float id = 1.0f / det;
        par[0] =  (b11*b22 - b12*b21) * id;
        par[1] = -(b01*b22 - b02*b21) * id;
        par[2] =  (b01*b12 - b02*b11) * id;
        par[3] = -(b10*b22 - b12*b20) * id;
        par[4] =  (b00*b22 - b02*b20) * id;
        par[5] = -(b00*b12 - b02*b10) * id;
        par[6] =  (b10*b21 - b11*b20) * id;
        par[7] = -(b00*b21 - b01*b20) * id;
        par[8] =  (b00*b11 - b01*b10) * id;
        float cut = *cutoff_p;
        par[9]  = cut * cut;
        par[10] = (*do_shift_p) ? (1.0f / cut) : 0.0f;
        constexpr float S = 1.0f / 65536.0f;
        par[11] = b00*S; par[12] = b01*S; par[13] = b02*S;
        par[14] = b10*S; par[15] = b11*S; par[16] = b12*S;
        par[17] = b20*S; par[18] = b21*S; par[19] = b22*S;
    }
}

// quantize: s = x @ boxInv in [0,1), u16 = round(s*65536) mod 65536
__global__ void pack_quant_kernel(const float* __restrict__ coords,
                                  const float* __restrict__ charges,
                                  const float* __restrict__ par,
                                  uint2* __restrict__ qatoms, int n) {
    int i = blockIdx.x * blockDim.x + threadIdx.x;
    if (i >= n) return;
    float x = coords[3*i], y = coords[3*i+1], z = coords[3*i+2];
    float sx = x*par[0] + y*par[3] + z*par[6];
    float sy = x*par[1] + y*par[4] + z*par[7];
    float sz = x*par[2] + y*par[5] + z*par[8];
    unsigned qx = (unsigned)__float2int_rn(sx * 65536.0f) & 0xFFFFu;
    unsigned qy = (unsigned)__float2int_rn(sy * 65536.0f) & 0xFFFFu;
    unsigned qz = (unsigned)__float2int_rn(sz * 65536.0f) & 0xFFFFu;
    unsigned qc = (unsigned)__half_as_ushort(__float2half(charges[i]));
    qatoms[i] = make_uint2(qx | (qy << 16), qz | (qc << 16));
}

__device__ __forceinline__ float pair_e_q(uint2 ri, uint2 rj, const float* P) {
    // integer minimum-image: low-16-bit wrap-around subtraction
    float dx = (float)(short)(ri.x - rj.x);
    float dy = (float)(short)((ri.x >> 16) - (rj.x >> 16));
    float dz = (float)(short)(ri.y - rj.y);
    float px = dx*P[11] + dy*P[14] + dz*P[17];
    float py = dx*P[12] + dy*P[15] + dz*P[18];
    float pz = dx*P[13] + dy*P[16] + dz*P[19];
    float r2 = px*px + py*py + pz*pz;
    float rinv = rsqrtf(r2);
    float qi = __half2float(__ushort_as_half((unsigned short)(ri.y >> 16)));
    float qj = __half2float(__ushort_as_half((unsigned short)(rj.y >> 16)));
    float e = qi * qj * (rinv - P[10]);
    return (r2 <= P[9]) ? e : 0.0f;
}

// ---------------- scatter ----------------

constexpr int S_TPB = 256;
constexpr int S_PPT = 8;
constexpr int S_PPB = S_TPB * S_PPT;   // 2048 pairs/block

__global__ __launch_bounds__(S_TPB)
void scatter_kernel(const int2* __restrict__ pairs, int npairs,
                    int nchunk, int nbucket,
                    unsigned* __restrict__ gcount,
                    unsigned* __restrict__ ovcount, int2* __restrict__ ovlist,
                    unsigned* __restrict__ bucket_data) {
    __shared__ unsigned hist[NBUCKET_MAX];
    for (int b = threadIdx.x; b < nbucket; b += S_TPB) hist[b] = 0u;
    __syncthreads();

    int base = blockIdx.x * S_PPB;
    int2 pr[S_PPT];
    int  bk[S_PPT];
#pragma unroll
    for (int u = 0; u < S_PPT; ++u) {
        int p = base + u * S_TPB + threadIdx.x;
        pr[u] = (p < npairs) ? pairs[p] : make_int2(-1, -1);
    }
#pragma unroll
    for (int u = 0; u < S_PPT; ++u) {
        bk[u] = (pr[u].x >= 0)
              ? (pr[u].x >> CHUNK_SHIFT) * nchunk + (pr[u].y >> CHUNK_SHIFT)
              : -1;
        if (bk[u] >= 0) atomicAdd(&hist[bk[u]], 1u);
    }
    __syncthreads();
    for (int b = threadIdx.x; b < nbucket; b += S_TPB) {
        unsigned c = hist[b];
        hist[b] = c ? atomicAdd(&gcount[b], c) : 0u;   // becomes abs cursor
    }
    __syncthreads();
#pragma unroll
    for (int u = 0; u < S_PPT; ++u) {
        if (bk[u] >= 0) {
            unsigned slot = atomicAdd(&hist[bk[u]], 1u);
            if (slot < (unsigned)CAP) {
                bucket_data[(size_t)bk[u] * CAP + slot] =
                    ((unsigned)(pr[u].x & (CHUNK - 1)) << 16) |
                     (unsigned)(pr[u].y & (CHUNK - 1));
            } else {
                unsigned o = atomicAdd(ovcount, 1u);
                if (o < (unsigned)OV_CAP) ovlist[o] = pr[u];
            }
        }
    }
}

// ---------------- per-bucket compute ----------------

constexpr int C_TPB = 1024;

__global__ __launch_bounds__(C_TPB)
void bucket_compute(const unsigned* __restrict__ bucket_data,
                    const unsigned* __restrict__ gcount,
                    const uint2* __restrict__ qatoms, int natoms, int nchunk,
                    const float* __restrict__ par, double* __restrict__ acc) {
    __shared__ uint2 tA[CHUNK];
    __shared__ uint2 tB[CHUNK];
    __shared__ double wsum[C_TPB / 64];

    float P[20];
#pragma unroll
    for (int k = 0; k < 20; ++k) P[k] = par[k];

    int b  = blockIdx.x;
    int bx = b / nchunk, by = b - bx * nchunk;
    int gx = bx << CHUNK_SHIFT, gy = by << CHUNK_SHIFT;

    for (int t = threadIdx.x; t < CHUNK; t += C_TPB) {
        int ga = gx + t;
        tA[t] = (ga < natoms) ? qatoms[ga] : make_uint2(0u, 0u);
        int gb = gy + t;
        tB[t] = (gb < natoms) ? qatoms[gb] : make_uint2(0u, 0u);
    }
    __syncthreads();

    int n = min((int)gcount[b], CAP);
    const unsigned* bd = bucket_data + (size_t)b * CAP;
    double lsum = 0.0;
    int t = threadIdx.x;
    for (; t + 3 * C_TPB < n; t += 4 * C_TPB) {
        unsigned k0 = bd[t];
        unsigned k1 = bd[t + C_TPB];
        unsigned k2 = bd[t + 2 * C_TPB];
        unsigned k3 = bd[t + 3 * C_TPB];
        float e0 = pair_e_q(tA[k0 >> 16], tB[k0 & 0xFFFFu], P);
        float e1 = pair_e_q(tA[k1 >> 16], tB[k1 & 0xFFFFu], P);
        float e2 = pair_e_q(tA[k2 >> 16], tB[k2 & 0xFFFFu], P);
        float e3 = pair_e_q(tA[k3 >> 16], tB[k3 & 0xFFFFu], P);
        lsum += (double)(e0 + e1) + (double)(e2 + e3);
    }
    for (; t < n; t += C_TPB) {
        unsigned k = bd[t];
        lsum += (double)pair_e_q(tA[k >> 16], tB[k & 0xFFFFu], P);
    }

#pragma unroll
    for (int off = 32; off > 0; off >>= 1)
        lsum += __shfl_down(lsum, off);

    int lane = threadIdx.x & 63;
    int wid  = threadIdx.x >> 6;
    if (lane == 0) wsum[wid] = lsum;
    __syncthreads();
    if (threadIdx.x == 0) {
        double s = 0.0;
#pragma unroll
        for (int w = 0; w < C_TPB / 64; ++w) s += wsum[w];
        atomicAdd(acc, s);
    }
}

__global__ void overflow_kernel(const int2* __restrict__ ovlist,
                                const unsigned* __restrict__ ovcount_p,
                                const uint2* __restrict__ qatoms,
                                const float* __restrict__ par,
                                double* __restrict__ acc) {
    float P[20];
#pragma unroll
    for (int k = 0; k < 20; ++k) P[k] = par[k];
    int n = (int)min(*ovcount_p, (unsigned)OV_CAP);
    double lsum = 0.0;
    for (int t = blockIdx.x * blockDim.x + threadIdx.x; t < n;
         t += gridDim.x * blockDim.x) {
        int2 pr = ovlist[t];
        lsum += (double)pair_e_q(qatoms[pr.x], qatoms[pr.y], P);
    }
#pragma unroll
    for (int off = 32; off > 0; off >>= 1)
        lsum += __shfl_down(lsum, off);
    __shared__ double wsum[TPB / 64];
    int lane = threadIdx.x & 63;
    int wid  = threadIdx.x >> 6;
    if (lane == 0) wsum[wid] = lsum;
    __syncthreads();
    if (threadIdx.x == 0) {
        double s = 0.0;
#pragma unroll
        for (int w = 0; w < TPB / 64; ++w) s += wsum[w];
        if (s != 0.0) atomicAdd(acc, s);
    }
}

// ---------------- fallback (direct gather, f32) ----------------

__device__ __forceinline__ float pair_e_f(float4 ai, float4 aj, const float* P,
                                          float c2, float shift) {
    float dx = ai.x - aj.x, dy = ai.y - aj.y, dz = ai.z - aj.z;
    float sx = dx*P[0] + dy*P[3] + dz*P[6];
    float sy = dx*P[1] + dy*P[4] + dz*P[7];
    float sz = dx*P[2] + dy*P[5] + dz*P[8];
    sx -= floorf(sx + 0.5f);
    sy -= floorf(sy + 0.5f);
    sz -= floorf(sz + 0.5f);
    float px = sx*P[11] + sy*P[14] + sz*P[17];
    float py = sx*P[12] + sy*P[15] + sz*P[18];
    float pz = sx*P[13] + sy*P[16] + sz*P[19];
    px *= 65536.0f; py *= 65536.0f; pz *= 65536.0f;  // par stores box/65536
    float r2 = px*px + py*py + pz*pz;
    float rinv = rsqrtf(r2);
    float e = ai.w * aj.w * (rinv - shift);
    return (r2 <= c2) ? e : 0.0f;
}

__global__ __launch_bounds__(TPB)
void coulomb_direct(const int2* __restrict__ pairs, int npairs,
                    const float* __restrict__ coords,
                    const float* __restrict__ charges,
                    const float* __restrict__ par,
                    double* __restrict__ acc) {
    float P[20];
#pragma unroll
    for (int k = 0; k < 20; ++k) P[k] = par[k];
    double lsum = 0.0;
    int tid = blockIdx.x * blockDim.x + threadIdx.x;
    int stride = gridDim.x * blockDim.x;
    for (int p = tid; p < npairs; p += stride) {
        int2 pr = pairs[p];
        float4 a = make_float4(coords[3*pr.x], coords[3*pr.x+1], coords[3*pr.x+2], charges[pr.x]);
        float4 c = make_float4(coords[3*pr.y], coords[3*pr.y+1], coords[3*pr.y+2], charges[pr.y]);
        lsum += (double)pair_e_f(a, c, P, P[9], P[10]);
    }
#pragma unroll
    for (int off = 32; off > 0; off >>= 1)
        lsum += __shfl_down(lsum, off);
    __shared__ double wsum[TPB / 64];
    int lane = threadIdx.x & 63;
    int wid  = threadIdx.x >> 6;
    if (lane == 0) wsum[wid] = lsum;
    __syncthreads();
    if (threadIdx.x == 0) {
        double s = 0.0;
#pragma unroll
        for (int w = 0; w < TPB / 64; ++w) s += wsum[w];
        atomicAdd(acc, s);
    }
}

__global__ void finalize_kernel(const double* __restrict__ acc,
                                const float* __restrict__ prefac_p,
                                float* __restrict__ out) {
    if (threadIdx.x == 0 && blockIdx.x == 0)
        out[0] = (float)(*acc * (double)(*prefac_p));
}

extern "C" void kernel_launch(void* const* d_in, const int* in_sizes, int n_in,
                              void* d_out, int out_size, void* d_ws, size_t ws_size,
                              hipStream_t stream) {
    const float* coords   = (const float*)d_in[0];
    const int*   pairs    = (const int*)d_in[1];
    const float* box      = (const float*)d_in[2];
    const float* charges  = (const float*)d_in[3];
    const float* prefac   = (const float*)d_in[4];
    const float* cutoff   = (const float*)d_in[5];
    const int*   do_shift = (const int*)d_in[6];
    float* out = (float*)d_out;

    int natoms = in_sizes[0] / 3;
    int npairs = in_sizes[1] / 2;

    double*   acc    = (double*)((char*)d_ws + WS_ACC);
    float*    par    = (float*)((char*)d_ws + WS_PAR);
    unsigned* gcount = (unsigned*)((char*)d_ws + WS_GCOUNT);
    unsigned* ovcnt  = (unsigned*)((char*)d_ws + WS_OVCNT);
    int2*     ovlist = (int2*)((char*)d_ws + WS_OVLIST);
    uint2*    qatoms = (uint2*)((char*)d_ws + WS_QATOMS);
    unsigned* bdata  = (unsigned*)((char*)d_ws + WS_BUCKET);

    int nchunk  = (natoms + CHUNK - 1) >> CHUNK_SHIFT;
    int nbucket = nchunk * nchunk;
    size_t need = WS_BUCKET + (size_t)nbucket * CAP * sizeof(unsigned);
    bool use_buckets = (nchunk <= NCHUNK_MAX) && (ws_size >= need);

    hipMemsetAsync(d_ws, 0, 4096, stream);
    setup_kernel<<<1, 64, 0, stream>>>(box, cutoff, do_shift, acc, par);

    if (use_buckets) {
        pack_quant_kernel<<<(natoms + TPB - 1) / TPB, TPB, 0, stream>>>(
            coords, charges, par, qatoms, natoms);

        int sblocks = (npairs + S_PPB - 1) / S_PPB;
        scatter_kernel<<<sblocks, S_TPB, 0, stream>>>(
            (const int2*)pairs, npairs, nchunk, nbucket,
            gcount, ovcnt, ovlist, bdata);

        bucket_compute<<<nbucket, C_TPB, 0, stream>>>(
            bdata, gcount, qatoms, natoms, nchunk, par, acc);

        overflow_kernel<<<8, TPB, 0, stream>>>(ovlist, ovcnt, qatoms, par, acc);
    } else {
        int blocks = (npairs + TPB - 1) / TPB;
        if (blocks > 2048) blocks = 2048;
        coulomb_direct<<<blocks, TPB, 0, stream>>>(
            (const int2*)pairs, npairs, coords, charges, par, acc);
    }

    finalize_kernel<<<1, 64, 0, stream>>>(acc, prefac, out);
}

// Round 5
// 83.555 us; speedup vs baseline: 1.2709x; 1.2709x over previous
//
#include <hip/hip_runtime.h>
#include <hip/hip_fp16.h>

// Coulomb pair-energy reduction via 2D pair bucketing + LDS-staged QUANTIZED
// atom tiles (8B records: u16 fractional x,y,z + f16 charge).
// R4: scatter redesign — fat blocks (15360 pairs) with LDS key/bucket stash,
// single HBM pass over pairs, short global-atomic reserve chains (417/bucket),
// SPLITx3 bucket compute for load balance.

constexpr int TPB = 256;

constexpr int CHUNK_SHIFT = 13;
constexpr int CHUNK       = 1 << CHUNK_SHIFT;   // 8192 atoms/chunk
constexpr int NCHUNK_MAX  = 15;                 // nbucket must be <= 254 (u8 marker)
constexpr int NBUCKET_MAX = 256;
constexpr int CAP         = 44032;              // mean 42950 + 5 sigma for 13x13
constexpr int OV_CAP      = 131072;

// ws layout (bytes)
constexpr size_t WS_ACC    = 0;         // double
constexpr size_t WS_PAR    = 16;        // float[24]
constexpr size_t WS_GCOUNT = 256;       // u32[NBUCKET_MAX]
constexpr size_t WS_OVCNT  = 1536;      // u32
constexpr size_t WS_OVLIST = 2048;      // int2[OV_CAP] ~1MB
constexpr size_t WS_QATOMS = 2u << 20;  // uint2[natoms]
constexpr size_t WS_BUCKET = 4u << 20;  // u32[nbucket*CAP]

// par: [0..8] boxInv, [9] cutoff^2, [10] shift, [11..19] box/65536
__global__ void setup_kernel(const float* __restrict__ box,
                             const float* __restrict__ cutoff_p,
                             const int* __restrict__ do_shift_p,
                             double* __restrict__ acc,
                             float* __restrict__ par) {
    if (threadIdx.x == 0 && blockIdx.x == 0) {
        *acc = 0.0;
        float b00 = box[0], b01 = box[1], b02 = box[2];
        float b10 = box[3], b11 = box[4], b12 = box[5];
        float b20 = box[6], b21 = box[7], b22 = box[8];
        float det = b00*(b11*b22 - b12*b21)
                  - b01*(b10*b22 - b12*b20)
                  + b02*(b10*b21 - b11*b20);
        float id = 1.0f / det;
        par[0] =  (b11*b22 - b12*b21) * id;
        par[1] = -(b01*b22 - b02*b21) * id;
        par[2] =  (b01*b12 - b02*b11) * id;
        par[3] = -(b10*b22 - b12*b20) * id;
        par[4] =  (b00*b22 - b02*b20) * id;
        par[5] = -(b00*b12 - b02*b10) * id;
        par[6] =  (b10*b21 - b11*b20) * id;
        par[7] = -(b00*b21 - b01*b20) * id;
        par[8] =  (b00*b11 - b01*b10) * id;
        float cut = *cutoff_p;
        par[9]  = cut * cut;
        par[10] = (*do_shift_p) ? (1.0f / cut) : 0.0f;
        constexpr float S = 1.0f / 65536.0f;
        par[11] = b00*S; par[12] = b01*S; par[13] = b02*S;
        par[14] = b10*S; par[15] = b11*S; par[16] = b12*S;
        par[17] = b20*S; par[18] = b21*S; par[19] = b22*S;
    }
}

// quantize: s = x @ boxInv, u16 = round(s*65536) mod 65536 (mod-1 wrap is exact)
__global__ void pack_quant_kernel(const float* __restrict__ coords,
                                  const float* __restrict__ charges,
                                  const float* __restrict__ par,
                                  uint2* __restrict__ qatoms, int n) {
    int i = blockIdx.x * blockDim.x + threadIdx.x;
    if (i >= n) return;
    float x = coords[3*i], y = coords[3*i+1], z = coords[3*i+2];
    float sx = x*par[0] + y*par[3] + z*par[6];
    float sy = x*par[1] + y*par[4] + z*par[7];
    float sz = x*par[2] + y*par[5] + z*par[8];
    unsigned qx = (unsigned)__float2int_rn(sx * 65536.0f) & 0xFFFFu;
    unsigned qy = (unsigned)__float2int_rn(sy * 65536.0f) & 0xFFFFu;
    unsigned qz = (unsigned)__float2int_rn(sz * 65536.0f) & 0xFFFFu;
    unsigned qc = (unsigned)__half_as_ushort(__float2half(charges[i]));
    qatoms[i] = make_uint2(qx | (qy << 16), qz | (qc << 16));
}

__device__ __forceinline__ float pair_e_q(uint2 ri, uint2 rj, const float* P) {
    // integer minimum-image: 16-bit wrap-around subtraction
    float dx = (float)(short)(ri.x - rj.x);
    float dy = (float)(short)((ri.x >> 16) - (rj.x >> 16));
    float dz = (float)(short)(ri.y - rj.y);
    float px = dx*P[11] + dy*P[14] + dz*P[17];
    float py = dx*P[12] + dy*P[15] + dz*P[18];
    float pz = dx*P[13] + dy*P[16] + dz*P[19];
    float r2 = px*px + py*py + pz*pz;
    float rinv = rsqrtf(r2);
    float qi = __half2float(__ushort_as_half((unsigned short)(ri.y >> 16)));
    float qj = __half2float(__ushort_as_half((unsigned short)(rj.y >> 16)));
    float e = qi * qj * (rinv - P[10]);
    return (r2 <= P[9]) ? e : 0.0f;
}

// ---------------- scatter: 1 HBM pass, LDS stash, short reserve chains ------

constexpr int S_TPB = 512;
constexpr int S_PPT = 30;
constexpr int S_PPB = S_TPB * S_PPT;   // 15360 pairs/block -> 417 blocks

__global__ __launch_bounds__(S_TPB)
void scatter_kernel(const int2* __restrict__ pairs, int npairs,
                    int nchunk, int nbucket,
                    unsigned* __restrict__ gcount,
                    unsigned* __restrict__ ovcount, int2* __restrict__ ovlist,
                    unsigned* __restrict__ bucket_data) {
    __shared__ unsigned      keys[S_PPB];   // (i&8191)<<16 | (j&8191)   60KB
    __shared__ unsigned char bks [S_PPB];   // bucket id, 255 = invalid  15KB
    __shared__ unsigned      hist[NBUCKET_MAX];

    for (int b = threadIdx.x; b < nbucket; b += S_TPB) hist[b] = 0u;
    __syncthreads();

    int base = blockIdx.x * S_PPB;
    // pass 1: stream pairs once from HBM; stash key+bucket in LDS; histogram
#pragma unroll 5
    for (int u = 0; u < S_PPT; ++u) {
        int idx = u * S_TPB + threadIdx.x;
        int p = base + idx;
        if (p < npairs) {
            int2 pr = pairs[p];
            int b = (pr.x >> CHUNK_SHIFT) * nchunk + (pr.y >> CHUNK_SHIFT);
            keys[idx] = ((unsigned)(pr.x & (CHUNK - 1)) << 16) |
                         (unsigned)(pr.y & (CHUNK - 1));
            bks[idx] = (unsigned char)b;
            atomicAdd(&hist[b], 1u);
        } else {
            bks[idx] = 255u;
        }
    }
    __syncthreads();
    // reserve: one global atomic per non-empty bucket (417-long chains max)
    for (int b = threadIdx.x; b < nbucket; b += S_TPB) {
        unsigned c = hist[b];
        hist[b] = c ? atomicAdd(&gcount[b], c) : 0u;   // becomes abs cursor
    }
    __syncthreads();
    // pass 2: replay from LDS, claim slot, write packed key
#pragma unroll 5
    for (int u = 0; u < S_PPT; ++u) {
        int idx = u * S_TPB + threadIdx.x;
        int b = (int)bks[idx];
        if (b != 255) {
            unsigned k = keys[idx];
            unsigned slot = atomicAdd(&hist[b], 1u);
            if (slot < (unsigned)CAP) {
                bucket_data[(size_t)b * CAP + slot] = k;
            } else {
                unsigned o = atomicAdd(ovcount, 1u);
                if (o < (unsigned)OV_CAP) {
                    int bi = b / nchunk, bj = b - bi * nchunk;
                    ovlist[o] = make_int2((bi << CHUNK_SHIFT) | (int)(k >> 16),
                                          (bj << CHUNK_SHIFT) | (int)(k & 0xFFFFu));
                }
            }
        }
    }
}

// ---------------- per-bucket compute (SPLIT-way for load balance) -----------

constexpr int C_TPB  = 1024;
constexpr int SPLIT  = 3;

__global__ __launch_bounds__(C_TPB)
void bucket_compute(const unsigned* __restrict__ bucket_data,
                    const unsigned* __restrict__ gcount,
                    const uint2* __restrict__ qatoms, int natoms, int nchunk,
                    const float* __restrict__ par, double* __restrict__ acc) {
    __shared__ uint2 tA[CHUNK];
    __shared__ uint2 tB[CHUNK];
    __shared__ double wsum[C_TPB / 64];

    float P[20];
#pragma unroll
    for (int k = 0; k < 20; ++k) P[k] = par[k];

    int b    = blockIdx.x / SPLIT;
    int part = blockIdx.x - b * SPLIT;
    int bx = b / nchunk, by = b - bx * nchunk;
    int gx = bx << CHUNK_SHIFT, gy = by << CHUNK_SHIFT;

    for (int t = threadIdx.x; t < CHUNK; t += C_TPB) {
        int ga = gx + t;
        tA[t] = (ga < natoms) ? qatoms[ga] : make_uint2(0u, 0u);
        int gb = gy + t;
        tB[t] = (gb < natoms) ? qatoms[gb] : make_uint2(0u, 0u);
    }
    __syncthreads();

    int n = min((int)gcount[b], CAP);
    const unsigned* bd = bucket_data + (size_t)b * CAP;
    constexpr int STRIDE = SPLIT * C_TPB;
    double lsum = 0.0;
    int t = part * C_TPB + threadIdx.x;
    for (; t + 3 * STRIDE < n; t += 4 * STRIDE) {
        unsigned k0 = bd[t];
        unsigned k1 = bd[t + STRIDE];
        unsigned k2 = bd[t + 2 * STRIDE];
        unsigned k3 = bd[t + 3 * STRIDE];
        float e0 = pair_e_q(tA[k0 >> 16], tB[k0 & 0xFFFFu], P);
        float e1 = pair_e_q(tA[k1 >> 16], tB[k1 & 0xFFFFu], P);
        float e2 = pair_e_q(tA[k2 >> 16], tB[k2 & 0xFFFFu], P);
        float e3 = pair_e_q(tA[k3 >> 16], tB[k3 & 0xFFFFu], P);
        lsum += (double)(e0 + e1) + (double)(e2 + e3);
    }
    for (; t < n; t += STRIDE) {
        unsigned k = bd[t];
        lsum += (double)pair_e_q(tA[k >> 16], tB[k & 0xFFFFu], P);
    }

#pragma unroll
    for (int off = 32; off > 0; off >>= 1)
        lsum += __shfl_down(lsum, off);

    int lane = threadIdx.x & 63;
    int wid  = threadIdx.x >> 6;
    if (lane == 0) wsum[wid] = lsum;
    __syncthreads();
    if (threadIdx.x == 0) {
        double s = 0.0;
#pragma unroll
        for (int w = 0; w < C_TPB / 64; ++w) s += wsum[w];
        atomicAdd(acc, s);
    }
}

__global__ void overflow_kernel(const int2* __restrict__ ovlist,
                                const unsigned* __restrict__ ovcount_p,
                                const uint2* __restrict__ qatoms,
                                const float* __restrict__ par,
                                double* __restrict__ acc) {
    float P[20];
#pragma unroll
    for (int k = 0; k < 20; ++k) P[k] = par[k];
    int n = (int)min(*ovcount_p, (unsigned)OV_CAP);
    double lsum = 0.0;
    for (int t = blockIdx.x * blockDim.x + threadIdx.x; t < n;
         t += gridDim.x * blockDim.x) {
        int2 pr = ovlist[t];
        lsum += (double)pair_e_q(qatoms[pr.x], qatoms[pr.y], P);
    }
#pragma unroll
    for (int off = 32; off > 0; off >>= 1)
        lsum += __shfl_down(lsum, off);
    __shared__ double wsum[TPB / 64];
    int lane = threadIdx.x & 63;
    int wid  = threadIdx.x >> 6;
    if (lane == 0) wsum[wid] = lsum;
    __syncthreads();
    if (threadIdx.x == 0) {
        double s = 0.0;
#pragma unroll
        for (int w = 0; w < TPB / 64; ++w) s += wsum[w];
        if (s != 0.0) atomicAdd(acc, s);
    }
}

// ---------------- fallback (direct gather, f32) ----------------

__device__ __forceinline__ float pair_e_f(float4 ai, float4 aj, const float* P,
                                          float c2, float shift) {
    float dx = ai.x - aj.x, dy = ai.y - aj.y, dz = ai.z - aj.z;
    float sx = dx*P[0] + dy*P[3] + dz*P[6];
    float sy = dx*P[1] + dy*P[4] + dz*P[7];
    float sz = dx*P[2] + dy*P[5] + dz*P[8];
    sx -= floorf(sx + 0.5f);
    sy -= floorf(sy + 0.5f);
    sz -= floorf(sz + 0.5f);
    float px = sx*P[11] + sy*P[14] + sz*P[17];
    float py = sx*P[12] + sy*P[15] + sz*P[18];
    float pz = sx*P[13] + sy*P[16] + sz*P[19];
    px *= 65536.0f; py *= 65536.0f; pz *= 65536.0f;  // par stores box/65536
    float r2 = px*px + py*py + pz*pz;
    float rinv = rsqrtf(r2);
    float e = ai.w * aj.w * (rinv - shift);
    return (r2 <= c2) ? e : 0.0f;
}

__global__ __launch_bounds__(TPB)
void coulomb_direct(const int2* __restrict__ pairs, int npairs,
                    const float* __restrict__ coords,
                    const float* __restrict__ charges,
                    const float* __restrict__ par,
                    double* __restrict__ acc) {
    float P[20];
#pragma unroll
    for (int k = 0; k < 20; ++k) P[k] = par[k];
    double lsum = 0.0;
    int tid = blockIdx.x * blockDim.x + threadIdx.x;
    int stride = gridDim.x * blockDim.x;
    for (int p = tid; p < npairs; p += stride) {
        int2 pr = pairs[p];
        float4 a = make_float4(coords[3*pr.x], coords[3*pr.x+1], coords[3*pr.x+2], charges[pr.x]);
        float4 c = make_float4(coords[3*pr.y], coords[3*pr.y+1], coords[3*pr.y+2], charges[pr.y]);
        lsum += (double)pair_e_f(a, c, P, P[9], P[10]);
    }
#pragma unroll
    for (int off = 32; off > 0; off >>= 1)
        lsum += __shfl_down(lsum, off);
    __shared__ double wsum[TPB / 64];
    int lane = threadIdx.x & 63;
    int wid  = threadIdx.x >> 6;
    if (lane == 0) wsum[wid] = lsum;
    __syncthreads();
    if (threadIdx.x == 0) {
        double s = 0.0;
#pragma unroll
        for (int w = 0; w < TPB / 64; ++w) s += wsum[w];
        atomicAdd(acc, s);
    }
}

__global__ void finalize_kernel(const double* __restrict__ acc,
                                const float* __restrict__ prefac_p,
                                float* __restrict__ out) {
    if (threadIdx.x == 0 && blockIdx.x == 0)
        out[0] = (float)(*acc * (double)(*prefac_p));
}

extern "C" void kernel_launch(void* const* d_in, const int* in_sizes, int n_in,
                              void* d_out, int out_size, void* d_ws, size_t ws_size,
                              hipStream_t stream) {
    const float* coords   = (const float*)d_in[0];
    const int*   pairs    = (const int*)d_in[1];
    const float* box      = (const float*)d_in[2];
    const float* charges  = (const float*)d_in[3];
    const float* prefac   = (const float*)d_in[4];
    const float* cutoff   = (const float*)d_in[5];
    const int*   do_shift = (const int*)d_in[6];
    float* out = (float*)d_out;

    int natoms = in_sizes[0] / 3;
    int npairs = in_sizes[1] / 2;

    double*   acc    = (double*)((char*)d_ws + WS_ACC);
    float*    par    = (float*)((char*)d_ws + WS_PAR);
    unsigned* gcount = (unsigned*)((char*)d_ws + WS_GCOUNT);
    unsigned* ovcnt  = (unsigned*)((char*)d_ws + WS_OVCNT);
    int2*     ovlist = (int2*)((char*)d_ws + WS_OVLIST);
    uint2*    qatoms = (uint2*)((char*)d_ws + WS_QATOMS);
    unsigned* bdata  = (unsigned*)((char*)d_ws + WS_BUCKET);

    int nchunk  = (natoms + CHUNK - 1) >> CHUNK_SHIFT;
    int nbucket = nchunk * nchunk;
    size_t need = WS_BUCKET + (size_t)nbucket * CAP * sizeof(unsigned);
    bool use_buckets = (nchunk <= NCHUNK_MAX) && (nbucket <= 254) &&
                       (ws_size >= need);

    hipMemsetAsync(d_ws, 0, 4096, stream);
    setup_kernel<<<1, 64, 0, stream>>>(box, cutoff, do_shift, acc, par);

    if (use_buckets) {
        pack_quant_kernel<<<(natoms + TPB - 1) / TPB, TPB, 0, stream>>>(
            coords, charges, par, qatoms, natoms);

        int sblocks = (npairs + S_PPB - 1) / S_PPB;
        scatter_kernel<<<sblocks, S_TPB, 0, stream>>>(
            (const int2*)pairs, npairs, nchunk, nbucket,
            gcount, ovcnt, ovlist, bdata);

        bucket_compute<<<nbucket * SPLIT, C_TPB, 0, stream>>>(
            bdata, gcount, qatoms, natoms, nchunk, par, acc);

        overflow_kernel<<<8, TPB, 0, stream>>>(ovlist, ovcnt, qatoms, par, acc);
    } else {
        int blocks = (npairs + TPB - 1) / TPB;
        if (blocks > 2048) blocks = 2048;
        coulomb_direct<<<blocks, TPB, 0, stream>>>(
            (const int2*)pairs, npairs, coords, charges, par, acc);
    }

    finalize_kernel<<<1, 64, 0, stream>>>(acc, prefac, out);
}

// Round 6
// 74.067 us; speedup vs baseline: 1.4337x; 1.1281x over previous
//
#include <hip/hip_runtime.h>
#include <hip/hip_fp16.h>

// Coulomb pair-energy reduction: 2D pair bucketing with ATOMIC-FREE block-major
// binning + LDS-staged quantized atom tiles (8B: u16 frac coords + f16 charge).
// R5: each scatter block sorts its 7680 pairs in LDS (hist->scan->scatter) and
// writes ONE coalesced burst + a 170-word offset row. No global atomics, no
// scattered global writes, no overflow path. Compute walks per-bucket segments.

constexpr int TPB = 256;

constexpr int CHUNK_SHIFT = 13;
constexpr int CHUNK       = 1 << CHUNK_SHIFT;   // 8192 atoms/chunk
constexpr int NCHUNK_MAX  = 15;                 // nbucket <= 225 (u8 marker 255)
constexpr int NB_MAX      = 256;

constexpr int S_TPB = 512;
constexpr int S_PPT = 15;
constexpr int S_PPB = S_TPB * S_PPT;            // 7680 pairs/block

constexpr int C_TPB   = 1024;
constexpr int C_SPLIT = 3;

// ws layout (bytes): [0,8) acc double; [16,16+21*4) par; table/qatoms/bdata dynamic
constexpr size_t WS_PAR   = 16;
constexpr size_t WS_TABLE = 4096;

// par: [0..8] boxInv, [9] cutoff^2, [10] shift, [11..19] box/65536, [20] diag flag
__global__ void setup_kernel(const float* __restrict__ box,
                             const float* __restrict__ cutoff_p,
                             const int* __restrict__ do_shift_p,
                             double* __restrict__ acc,
                             float* __restrict__ par) {
    if (threadIdx.x == 0 && blockIdx.x == 0) {
        *acc = 0.0;
        float b00 = box[0], b01 = box[1], b02 = box[2];
        float b10 = box[3], b11 = box[4], b12 = box[5];
        float b20 = box[6], b21 = box[7], b22 = box[8];
        float det = b00*(b11*b22 - b12*b21)
                  - b01*(b10*b22 - b12*b20)
                  + b02*(b10*b21 - b11*b20);
        float id = 1.0f / det;
        par[0] =  (b11*b22 - b12*b21) * id;
        par[1] = -(b01*b22 - b02*b21) * id;
        par[2] =  (b01*b12 - b02*b11) * id;
        par[3] = -(b10*b22 - b12*b20) * id;
        par[4] =  (b00*b22 - b02*b20) * id;
        par[5] = -(b00*b12 - b02*b10) * id;
        par[6] =  (b10*b21 - b11*b20) * id;
        par[7] = -(b00*b21 - b01*b20) * id;
        par[8] =  (b00*b11 - b01*b10) * id;
        float cut = *cutoff_p;
        par[9]  = cut * cut;
        par[10] = (*do_shift_p) ? (1.0f / cut) : 0.0f;
        constexpr float S = 1.0f / 65536.0f;
        par[11] = b00*S; par[12] = b01*S; par[13] = b02*S;
        par[14] = b10*S; par[15] = b11*S; par[16] = b12*S;
        par[17] = b20*S; par[18] = b21*S; par[19] = b22*S;
        float offd = fabsf(b01) + fabsf(b02) + fabsf(b10)
                   + fabsf(b12) + fabsf(b20) + fabsf(b21);
        par[20] = (offd == 0.0f) ? 1.0f : 0.0f;
    }
}

// quantize: s = x @ boxInv, u16 = round(s*65536) mod 65536 (mod-1 wrap exact)
__global__ void pack_quant_kernel(const float* __restrict__ coords,
                                  const float* __restrict__ charges,
                                  const float* __restrict__ par,
                                  uint2* __restrict__ qatoms, int n) {
    int i = blockIdx.x * blockDim.x + threadIdx.x;
    if (i >= n) return;
    float x = coords[3*i], y = coords[3*i+1], z = coords[3*i+2];
    float sx = x*par[0] + y*par[3] + z*par[6];
    float sy = x*par[1] + y*par[4] + z*par[7];
    float sz = x*par[2] + y*par[5] + z*par[8];
    unsigned qx = (unsigned)__float2int_rn(sx * 65536.0f) & 0xFFFFu;
    unsigned qy = (unsigned)__float2int_rn(sy * 65536.0f) & 0xFFFFu;
    unsigned qz = (unsigned)__float2int_rn(sz * 65536.0f) & 0xFFFFu;
    unsigned qc = (unsigned)__half_as_ushort(__float2half(charges[i]));
    qatoms[i] = make_uint2(qx | (qy << 16), qz | (qc << 16));
}

// ---------------- scatter: atomic-free, block-major, coalesced -------------

__global__ __launch_bounds__(S_TPB)
void scatter_kernel(const int2* __restrict__ pairs, int npairs, int nchunk,
                    int nbucket, int NBp,
                    unsigned* __restrict__ table,
                    unsigned* __restrict__ bdata) {
    __shared__ __align__(16) unsigned keys[S_PPB];   // 30KB; reused as ordered
    __shared__ unsigned char bks[S_PPB];             // 7.5KB
    __shared__ unsigned hist[NB_MAX];
    __shared__ unsigned sA[NB_MAX], sB[NB_MAX];
    __shared__ unsigned cur[NB_MAX];

    int tid = threadIdx.x;
    int blk = blockIdx.x;
    for (int t = tid; t < NB_MAX; t += S_TPB) hist[t] = 0u;
    __syncthreads();

    int base = blk * S_PPB;
    // pass 1: stream pairs, stash key+bucket in LDS, LDS histogram
#pragma unroll 5
    for (int u = 0; u < S_PPT; ++u) {
        int idx = u * S_TPB + tid;
        int p = base + idx;
        if (p < npairs) {
            int2 pr = pairs[p];
            int bb = (pr.x >> CHUNK_SHIFT) * nchunk + (pr.y >> CHUNK_SHIFT);
            keys[idx] = ((unsigned)(pr.x & (CHUNK - 1)) << 16) |
                         (unsigned)(pr.y & (CHUNK - 1));
            bks[idx] = (unsigned char)bb;
            atomicAdd(&hist[bb], 1u);
        } else {
            bks[idx] = 255u;
        }
    }
    __syncthreads();

    // exclusive scan (Hillis-Steele, ping-pong)
    unsigned *pa = sA, *pb = sB;
    if (tid < NB_MAX) pa[tid] = hist[tid];
    __syncthreads();
    for (int d = 1; d < NB_MAX; d <<= 1) {
        if (tid < NB_MAX) {
            unsigned v = pa[tid];
            if (tid >= d) v += pa[tid - d];
            pb[tid] = v;
        }
        __syncthreads();
        unsigned* t = pa; pa = pb; pb = t;
    }
    // pa = inclusive scan; write table row + init cursors
    if (tid <= nbucket) {
        unsigned excl = (tid == 0) ? 0u : pa[tid - 1];
        table[(size_t)blk * NBp + tid] = excl;   // tid==nbucket -> total
        if (tid < nbucket) cur[tid] = excl;
    }
    __syncthreads();

    // pass 2a: LDS -> registers (so keys[] can be reused as ordered buffer)
    unsigned k[S_PPT];
    int bb[S_PPT];
#pragma unroll
    for (int u = 0; u < S_PPT; ++u) {
        int idx = u * S_TPB + tid;
        k[u] = keys[idx];
        bb[u] = (int)bks[idx];
    }
    __syncthreads();
    // pass 2b: LDS scatter into bucket-ordered positions
#pragma unroll
    for (int u = 0; u < S_PPT; ++u) {
        if (bb[u] != 255) {
            unsigned slot = atomicAdd(&cur[bb[u]], 1u);
            keys[slot] = k[u];
        }
    }
    __syncthreads();

    // coalesced burst writeout of this block's ordered pairs
    unsigned total = pa[nbucket - 1];
    unsigned* dst = bdata + (size_t)blk * S_PPB;
    unsigned n4 = total >> 2;
    const uint4* k4 = (const uint4*)keys;
    for (unsigned i = tid; i < n4; i += S_TPB)
        ((uint4*)dst)[i] = k4[i];
    for (unsigned i = (n4 << 2) + tid; i < total; i += S_TPB)
        dst[i] = keys[i];
}

// ---------------- per-bucket compute ----------------

template<bool DIAG>
__device__ __forceinline__ double
seg_walk(const unsigned* __restrict__ tbl, int NBp, int b,
         const unsigned* __restrict__ bdata, int s0, int s1,
         int wid, int lane, int NW,
         const uint2* tA, const uint2* tB, const float* P) {
    double lsum = 0.0;
    int s = s0 + wid;
    unsigned off = 0, end = 0;
    if (s < s1) { off = tbl[(size_t)s * NBp + b]; end = tbl[(size_t)s * NBp + b + 1]; }
    while (s < s1) {
        int sn = s + NW;
        unsigned offn = 0, endn = 0;
        if (sn < s1) { offn = tbl[(size_t)sn * NBp + b]; endn = tbl[(size_t)sn * NBp + b + 1]; }
        const unsigned* src = bdata + (size_t)s * S_PPB;
        for (unsigned e = off + (unsigned)lane; e < end; e += 64u) {
            unsigned key = src[e];
            uint2 ri = tA[key >> 16];
            uint2 rj = tB[key & 0xFFFFu];
            float dx = (float)(short)(ri.x - rj.x);
            float dy = (float)(short)((ri.x >> 16) - (rj.x >> 16));
            float dz = (float)(short)(ri.y - rj.y);
            float px, py, pz;
            if (DIAG) {
                px = dx * P[11]; py = dy * P[15]; pz = dz * P[19];
            } else {
                px = dx*P[11] + dy*P[14] + dz*P[17];
                py = dx*P[12] + dy*P[15] + dz*P[18];
                pz = dx*P[13] + dy*P[16] + dz*P[19];
            }
            float r2 = px*px + py*py + pz*pz;
            float rinv = rsqrtf(r2);
            float qi = __half2float(__ushort_as_half((unsigned short)(ri.y >> 16)));
            float qj = __half2float(__ushort_as_half((unsigned short)(rj.y >> 16)));
            float e_ = qi * qj * (rinv - P[10]);
            lsum += (double)((r2 <= P[9]) ? e_ : 0.0f);
        }
        s = sn; off = offn; end = endn;
    }
    return lsum;
}

__global__ __launch_bounds__(C_TPB)
void bucket_compute(const unsigned* __restrict__ bdata,
                    const unsigned* __restrict__ table, int NBp, int nsb,
                    const uint2* __restrict__ qatoms, int natoms, int nchunk,
                    const float* __restrict__ par, double* __restrict__ acc) {
    __shared__ uint2 tA[CHUNK];
    __shared__ uint2 tB[CHUNK];
    __shared__ double wsum[C_TPB / 64];

    float P[21];
#pragma unroll
    for (int k = 0; k < 21; ++k) P[k] = par[k];

    int b    = blockIdx.x / C_SPLIT;
    int part = blockIdx.x - b * C_SPLIT;
    int bx = b / nchunk, by = b - bx * nchunk;
    int gx = bx << CHUNK_SHIFT, gy = by << CHUNK_SHIFT;

    for (int t = threadIdx.x; t < CHUNK; t += C_TPB) {
        int ga = gx + t;
        tA[t] = (ga < natoms) ? qatoms[ga] : make_uint2(0u, 0u);
        int gb = gy + t;
        tB[t] = (gb < natoms) ? qatoms[gb] : make_uint2(0u, 0u);
    }
    __syncthreads();

    int s0 = (int)(((long long)part * nsb) / C_SPLIT);
    int s1 = (int)(((long long)(part + 1) * nsb) / C_SPLIT);
    int lane = threadIdx.x & 63;
    int wid  = threadIdx.x >> 6;
    constexpr int NW = C_TPB / 64;

    double lsum = (P[20] != 0.0f)
        ? seg_walk<true >(table, NBp, b, bdata, s0, s1, wid, lane, NW, tA, tB, P)
        : seg_walk<false>(table, NBp, b, bdata, s0, s1, wid, lane, NW, tA, tB, P);

#pragma unroll
    for (int off = 32; off > 0; off >>= 1)
        lsum += __shfl_down(lsum, off);

    if (lane == 0) wsum[wid] = lsum;
    __syncthreads();
    if (threadIdx.x == 0) {
        double s = 0.0;
#pragma unroll
        for (int w = 0; w < NW; ++w) s += wsum[w];
        atomicAdd(acc, s);
    }
}

// ---------------- fallback (direct gather, f32) ----------------

__device__ __forceinline__ float pair_e_f(float4 ai, float4 aj, const float* P,
                                          float c2, float shift) {
    float dx = ai.x - aj.x, dy = ai.y - aj.y, dz = ai.z - aj.z;
    float sx = dx*P[0] + dy*P[3] + dz*P[6];
    float sy = dx*P[1] + dy*P[4] + dz*P[7];
    float sz = dx*P[2] + dy*P[5] + dz*P[8];
    sx -= floorf(sx + 0.5f);
    sy -= floorf(sy + 0.5f);
    sz -= floorf(sz + 0.5f);
    float px = sx*P[11] + sy*P[14] + sz*P[17];
    float py = sx*P[12] + sy*P[15] + sz*P[18];
    float pz = sx*P[13] + sy*P[16] + sz*P[19];
    px *= 65536.0f; py *= 65536.0f; pz *= 65536.0f;  // par stores box/65536
    float r2 = px*px + py*py + pz*pz;
    float rinv = rsqrtf(r2);
    float e = ai.w * aj.w * (rinv - shift);
    return (r2 <= c2) ? e : 0.0f;
}

__global__ __launch_bounds__(TPB)
void coulomb_direct(const int2* __restrict__ pairs, int npairs,
                    const float* __restrict__ coords,
                    const float* __restrict__ charges,
                    const float* __restrict__ par,
                    double* __restrict__ acc) {
    float P[20];
#pragma unroll
    for (int k = 0; k < 20; ++k) P[k] = par[k];
    double lsum = 0.0;
    int tid = blockIdx.x * blockDim.x + threadIdx.x;
    int stride = gridDim.x * blockDim.x;
    for (int p = tid; p < npairs; p += stride) {
        int2 pr = pairs[p];
        float4 a = make_float4(coords[3*pr.x], coords[3*pr.x+1], coords[3*pr.x+2], charges[pr.x]);
        float4 c = make_float4(coords[3*pr.y], coords[3*pr.y+1], coords[3*pr.y+2], charges[pr.y]);
        lsum += (double)pair_e_f(a, c, P, P[9], P[10]);
    }
#pragma unroll
    for (int off = 32; off > 0; off >>= 1)
        lsum += __shfl_down(lsum, off);
    __shared__ double wsum[TPB / 64];
    int lane = threadIdx.x & 63;
    int wid  = threadIdx.x >> 6;
    if (lane == 0) wsum[wid] = lsum;
    __syncthreads();
    if (threadIdx.x == 0) {
        double s = 0.0;
#pragma unroll
        for (int w = 0; w < TPB / 64; ++w) s += wsum[w];
        atomicAdd(acc, s);
    }
}

__global__ void finalize_kernel(const double* __restrict__ acc,
                                const float* __restrict__ prefac_p,
                                float* __restrict__ out) {
    if (threadIdx.x == 0 && blockIdx.x == 0)
        out[0] = (float)(*acc * (double)(*prefac_p));
}

extern "C" void kernel_launch(void* const* d_in, const int* in_sizes, int n_in,
                              void* d_out, int out_size, void* d_ws, size_t ws_size,
                              hipStream_t stream) {
    const float* coords   = (const float*)d_in[0];
    const int*   pairs    = (const int*)d_in[1];
    const float* box      = (const float*)d_in[2];
    const float* charges  = (const float*)d_in[3];
    const float* prefac   = (const float*)d_in[4];
    const float* cutoff   = (const float*)d_in[5];
    const int*   do_shift = (const int*)d_in[6];
    float* out = (float*)d_out;

    int natoms = in_sizes[0] / 3;
    int npairs = in_sizes[1] / 2;

    double* acc = (double*)d_ws;
    float*  par = (float*)((char*)d_ws + WS_PAR);

    int nchunk  = (natoms + CHUNK - 1) >> CHUNK_SHIFT;
    int nbucket = nchunk * nchunk;
    int NBp     = nbucket + 1;
    int nsb     = (npairs + S_PPB - 1) / S_PPB;

    size_t off_table  = WS_TABLE;
    size_t table_b    = (size_t)nsb * NBp * sizeof(unsigned);
    size_t off_qatoms = (off_table + table_b + 255) & ~(size_t)255;
    size_t off_bdata  = (off_qatoms + (size_t)natoms * sizeof(uint2) + 255) & ~(size_t)255;
    size_t need       = off_bdata + (size_t)npairs * sizeof(unsigned);

    bool use_buckets = (nchunk <= NCHUNK_MAX) && (nbucket <= 254) &&
                       (ws_size >= need);

    setup_kernel<<<1, 64, 0, stream>>>(box, cutoff, do_shift, acc, par);

    if (use_buckets) {
        unsigned* table  = (unsigned*)((char*)d_ws + off_table);
        uint2*    qatoms = (uint2*)((char*)d_ws + off_qatoms);
        unsigned* bdata  = (unsigned*)((char*)d_ws + off_bdata);

        pack_quant_kernel<<<(natoms + TPB - 1) / TPB, TPB, 0, stream>>>(
            coords, charges, par, qatoms, natoms);

        scatter_kernel<<<nsb, S_TPB, 0, stream>>>(
            (const int2*)pairs, npairs, nchunk, nbucket, NBp, table, bdata);

        bucket_compute<<<nbucket * C_SPLIT, C_TPB, 0, stream>>>(
            bdata, table, NBp, nsb, qatoms, natoms, nchunk, par, acc);
    } else {
        int blocks = (npairs + TPB - 1) / TPB;
        if (blocks > 2048) blocks = 2048;
        coulomb_direct<<<blocks, TPB, 0, stream>>>(
            (const int2*)pairs, npairs, coords, charges, par, acc);
    }

    finalize_kernel<<<1, 64, 0, stream>>>(acc, prefac, out);
}

// Round 7
// 66.413 us; speedup vs baseline: 1.5989x; 1.1152x over previous
//
#include <hip/hip_runtime.h>
#include <hip/hip_fp16.h>

// Coulomb pair-energy reduction: 2D pair bucketing with atomic-free block-major
// binning + LDS-staged quantized atom tiles (8B: u16 frac coords + f16 charge).
// R6: bucket_compute latency-chain fix — transposed offsets table (coalesced
// 64-segment offset loads) + run-unrolled independent key-slice reads (4 deep).

constexpr int TPB = 256;

constexpr int CHUNK_SHIFT = 13;
constexpr int CHUNK       = 1 << CHUNK_SHIFT;   // 8192 atoms/chunk
constexpr int NCHUNK_MAX  = 15;                 // nbucket <= 225 (u8 marker 255)
constexpr int NB_MAX      = 256;

constexpr int S_TPB = 512;
constexpr int S_PPT = 15;
constexpr int S_PPB = S_TPB * S_PPT;            // 7680 pairs/block

constexpr int C_TPB   = 1024;
constexpr int C_SPLIT = 3;
constexpr int C_NW    = C_TPB / 64;

// ws layout (bytes): [0,8) acc double; [16,16+21*4) par; tableT/qatoms/bdata dynamic
constexpr size_t WS_PAR   = 16;
constexpr size_t WS_TABLE = 4096;

// par: [0..8] boxInv, [9] cutoff^2, [10] shift, [11..19] box/65536, [20] diag flag
__global__ void setup_kernel(const float* __restrict__ box,
                             const float* __restrict__ cutoff_p,
                             const int* __restrict__ do_shift_p,
                             double* __restrict__ acc,
                             float* __restrict__ par) {
    if (threadIdx.x == 0 && blockIdx.x == 0) {
        *acc = 0.0;
        float b00 = box[0], b01 = box[1], b02 = box[2];
        float b10 = box[3], b11 = box[4], b12 = box[5];
        float b20 = box[6], b21 = box[7], b22 = box[8];
        float det = b00*(b11*b22 - b12*b21)
                  - b01*(b10*b22 - b12*b20)
                  + b02*(b10*b21 - b11*b20);
        float id = 1.0f / det;
        par[0] =  (b11*b22 - b12*b21) * id;
        par[1] = -(b01*b22 - b02*b21) * id;
        par[2] =  (b01*b12 - b02*b11) * id;
        par[3] = -(b10*b22 - b12*b20) * id;
        par[4] =  (b00*b22 - b02*b20) * id;
        par[5] = -(b00*b12 - b02*b10) * id;
        par[6] =  (b10*b21 - b11*b20) * id;
        par[7] = -(b00*b21 - b01*b20) * id;
        par[8] =  (b00*b11 - b01*b10) * id;
        float cut = *cutoff_p;
        par[9]  = cut * cut;
        par[10] = (*do_shift_p) ? (1.0f / cut) : 0.0f;
        constexpr float S = 1.0f / 65536.0f;
        par[11] = b00*S; par[12] = b01*S; par[13] = b02*S;
        par[14] = b10*S; par[15] = b11*S; par[16] = b12*S;
        par[17] = b20*S; par[18] = b21*S; par[19] = b22*S;
        float offd = fabsf(b01) + fabsf(b02) + fabsf(b10)
                   + fabsf(b12) + fabsf(b20) + fabsf(b21);
        par[20] = (offd == 0.0f) ? 1.0f : 0.0f;
    }
}

// quantize: s = x @ boxInv, u16 = round(s*65536) mod 65536 (mod-1 wrap exact)
__global__ void pack_quant_kernel(const float* __restrict__ coords,
                                  const float* __restrict__ charges,
                                  const float* __restrict__ par,
                                  uint2* __restrict__ qatoms, int n) {
    int i = blockIdx.x * blockDim.x + threadIdx.x;
    if (i >= n) return;
    float x = coords[3*i], y = coords[3*i+1], z = coords[3*i+2];
    float sx = x*par[0] + y*par[3] + z*par[6];
    float sy = x*par[1] + y*par[4] + z*par[7];
    float sz = x*par[2] + y*par[5] + z*par[8];
    unsigned qx = (unsigned)__float2int_rn(sx * 65536.0f) & 0xFFFFu;
    unsigned qy = (unsigned)__float2int_rn(sy * 65536.0f) & 0xFFFFu;
    unsigned qz = (unsigned)__float2int_rn(sz * 65536.0f) & 0xFFFFu;
    unsigned qc = (unsigned)__half_as_ushort(__float2half(charges[i]));
    qatoms[i] = make_uint2(qx | (qy << 16), qz | (qc << 16));
}

// ---------------- scatter: atomic-free, block-major, coalesced -------------

__global__ __launch_bounds__(S_TPB)
void scatter_kernel(const int2* __restrict__ pairs, int npairs, int nchunk,
                    int nbucket, int nsb,
                    unsigned* __restrict__ tableT,   // [nbucket+1][nsb]
                    unsigned* __restrict__ bdata) {
    __shared__ __align__(16) unsigned keys[S_PPB];   // 30KB; reused as ordered
    __shared__ unsigned char bks[S_PPB];             // 7.5KB
    __shared__ unsigned hist[NB_MAX];
    __shared__ unsigned sA[NB_MAX], sB[NB_MAX];
    __shared__ unsigned cur[NB_MAX];

    int tid = threadIdx.x;
    int blk = blockIdx.x;
    for (int t = tid; t < NB_MAX; t += S_TPB) hist[t] = 0u;
    __syncthreads();

    int base = blk * S_PPB;
    // pass 1: stream pairs, stash key+bucket in LDS, LDS histogram
#pragma unroll 5
    for (int u = 0; u < S_PPT; ++u) {
        int idx = u * S_TPB + tid;
        int p = base + idx;
        if (p < npairs) {
            int2 pr = pairs[p];
            int bb = (pr.x >> CHUNK_SHIFT) * nchunk + (pr.y >> CHUNK_SHIFT);
            keys[idx] = ((unsigned)(pr.x & (CHUNK - 1)) << 16) |
                         (unsigned)(pr.y & (CHUNK - 1));
            bks[idx] = (unsigned char)bb;
            atomicAdd(&hist[bb], 1u);
        } else {
            bks[idx] = 255u;
        }
    }
    __syncthreads();

    // exclusive scan (Hillis-Steele, ping-pong)
    unsigned *pa = sA, *pb = sB;
    if (tid < NB_MAX) pa[tid] = hist[tid];
    __syncthreads();
    for (int d = 1; d < NB_MAX; d <<= 1) {
        if (tid < NB_MAX) {
            unsigned v = pa[tid];
            if (tid >= d) v += pa[tid - d];
            pb[tid] = v;
        }
        __syncthreads();
        unsigned* t = pa; pa = pb; pb = t;
    }
    // pa = inclusive scan; write TRANSPOSED table row + init cursors
    if (tid <= nbucket) {
        unsigned excl = (tid == 0) ? 0u : pa[tid - 1];
        tableT[(size_t)tid * nsb + blk] = excl;
        if (tid < nbucket) cur[tid] = excl;
    }
    __syncthreads();

    // pass 2a: LDS -> registers (so keys[] can be reused as ordered buffer)
    unsigned k[S_PPT];
    int bb[S_PPT];
#pragma unroll
    for (int u = 0; u < S_PPT; ++u) {
        int idx = u * S_TPB + tid;
        k[u] = keys[idx];
        bb[u] = (int)bks[idx];
    }
    __syncthreads();
    // pass 2b: LDS scatter into bucket-ordered positions
#pragma unroll
    for (int u = 0; u < S_PPT; ++u) {
        if (bb[u] != 255) {
            unsigned slot = atomicAdd(&cur[bb[u]], 1u);
            keys[slot] = k[u];
        }
    }
    __syncthreads();

    // coalesced burst writeout of this block's ordered pairs
    unsigned total = pa[nbucket - 1];
    unsigned* dst = bdata + (size_t)blk * S_PPB;
    unsigned n4 = total >> 2;
    const uint4* k4 = (const uint4*)keys;
    for (unsigned i = tid; i < n4; i += S_TPB)
        ((uint4*)dst)[i] = k4[i];
    for (unsigned i = (n4 << 2) + tid; i < total; i += S_TPB)
        dst[i] = keys[i];
}

// ---------------- per-bucket compute ----------------

template<bool DIAG>
__device__ __forceinline__ float pair_ener(const uint2* tA, const uint2* tB,
                                           unsigned key, const float* P,
                                           bool valid) {
    uint2 ri = tA[key >> 16];
    uint2 rj = tB[key & 0xFFFFu];
    float dx = (float)(short)(ri.x - rj.x);
    float dy = (float)(short)((ri.x >> 16) - (rj.x >> 16));
    float dz = (float)(short)(ri.y - rj.y);
    float px, py, pz;
    if (DIAG) {
        px = dx * P[11]; py = dy * P[15]; pz = dz * P[19];
    } else {
        px = dx*P[11] + dy*P[14] + dz*P[17];
        py = dx*P[12] + dy*P[15] + dz*P[18];
        pz = dx*P[13] + dy*P[16] + dz*P[19];
    }
    float r2 = px*px + py*py + pz*pz;
    float rinv = rsqrtf(r2);
    float qi = __half2float(__ushort_as_half((unsigned short)(ri.y >> 16)));
    float qj = __half2float(__ushort_as_half((unsigned short)(rj.y >> 16)));
    float e = qi * qj * (rinv - P[10]);
    return (valid && r2 <= P[9]) ? e : 0.0f;
}

template<bool DIAG>
__global__ __launch_bounds__(C_TPB)
void bucket_compute(const unsigned* __restrict__ bdata,
                    const unsigned* __restrict__ tableT, int nsb,
                    const uint2* __restrict__ qatoms, int natoms, int nchunk,
                    const float* __restrict__ par, double* __restrict__ acc) {
    __shared__ uint2 tA[CHUNK];
    __shared__ uint2 tB[CHUNK];
    __shared__ double wsum[C_NW];

    float P[21];
#pragma unroll
    for (int k = 0; k < 21; ++k) P[k] = par[k];

    int b    = blockIdx.x / C_SPLIT;
    int part = blockIdx.x - b * C_SPLIT;
    int bx = b / nchunk, by = b - bx * nchunk;
    int gx = bx << CHUNK_SHIFT, gy = by << CHUNK_SHIFT;

    for (int t = threadIdx.x; t < CHUNK; t += C_TPB) {
        int ga = gx + t;
        tA[t] = (ga < natoms) ? qatoms[ga] : make_uint2(0u, 0u);
        int gb = gy + t;
        tB[t] = (gb < natoms) ? qatoms[gb] : make_uint2(0u, 0u);
    }
    __syncthreads();

    int s0 = (int)(((long long)part * nsb) / C_SPLIT);
    int s1 = (int)(((long long)(part + 1) * nsb) / C_SPLIT);
    int lane = threadIdx.x & 63;
    int wid  = threadIdx.x >> 6;

    int nseg = s1 - s0;
    int spw  = (nseg + C_NW - 1) / C_NW;        // segments per wave
    int sA0  = s0 + wid * spw;
    int cnt  = min(spw, s1 - sA0);
    if (cnt < 0) cnt = 0;

    const unsigned* rowB  = tableT + (size_t)b * nsb;
    const unsigned* rowB1 = tableT + (size_t)(b + 1) * nsb;

    double lsum0 = 0.0, lsum1 = 0.0;

    for (int batch = 0; batch < cnt; batch += 64) {
        int bc = min(64, cnt - batch);
        // coalesced offset loads for up to 64 segments
        unsigned o0v = 0u, lnv = 0u;
        if (lane < bc) {
            int s = sA0 + batch + lane;
            unsigned a0 = rowB[s];
            unsigned a1 = rowB1[s];
            o0v = a0;
            lnv = a1 - a0;
        }
        for (int k = 0; k < bc; k += 4) {
            unsigned off0 = (unsigned)__shfl((int)o0v, k);
            unsigned len0 = (k     < bc) ? (unsigned)__shfl((int)lnv, k)     : 0u;
            unsigned off1 = (unsigned)__shfl((int)o0v, k + 1);
            unsigned len1 = (k + 1 < bc) ? (unsigned)__shfl((int)lnv, k + 1) : 0u;
            unsigned off2 = (unsigned)__shfl((int)o0v, k + 2);
            unsigned len2 = (k + 2 < bc) ? (unsigned)__shfl((int)lnv, k + 2) : 0u;
            unsigned off3 = (unsigned)__shfl((int)o0v, k + 3);
            unsigned len3 = (k + 3 < bc) ? (unsigned)__shfl((int)lnv, k + 3) : 0u;
            size_t base0 = (size_t)(sA0 + batch + k    ) * S_PPB + off0;
            size_t base1 = (size_t)(sA0 + batch + k + 1) * S_PPB + off1;
            size_t base2 = (size_t)(sA0 + batch + k + 2) * S_PPB + off2;
            size_t base3 = (size_t)(sA0 + batch + k + 3) * S_PPB + off3;
            // issue 4 independent run reads
            unsigned k0 = (lane < (int)len0) ? bdata[base0 + lane] : 0u;
            unsigned k1 = (lane < (int)len1) ? bdata[base1 + lane] : 0u;
            unsigned k2 = (lane < (int)len2) ? bdata[base2 + lane] : 0u;
            unsigned k3 = (lane < (int)len3) ? bdata[base3 + lane] : 0u;
            // compute 4
            lsum0 += (double)pair_ener<DIAG>(tA, tB, k0, P, lane < (int)len0);
            lsum1 += (double)pair_ener<DIAG>(tA, tB, k1, P, lane < (int)len1);
            lsum0 += (double)pair_ener<DIAG>(tA, tB, k2, P, lane < (int)len2);
            lsum1 += (double)pair_ener<DIAG>(tA, tB, k3, P, lane < (int)len3);
            // rare tails (run longer than 64)
            if (len0 > 64u) for (unsigned e = 64u + lane; e < len0; e += 64u)
                lsum0 += (double)pair_ener<DIAG>(tA, tB, bdata[base0 + e], P, true);
            if (len1 > 64u) for (unsigned e = 64u + lane; e < len1; e += 64u)
                lsum1 += (double)pair_ener<DIAG>(tA, tB, bdata[base1 + e], P, true);
            if (len2 > 64u) for (unsigned e = 64u + lane; e < len2; e += 64u)
                lsum0 += (double)pair_ener<DIAG>(tA, tB, bdata[base2 + e], P, true);
            if (len3 > 64u) for (unsigned e = 64u + lane; e < len3; e += 64u)
                lsum1 += (double)pair_ener<DIAG>(tA, tB, bdata[base3 + e], P, true);
        }
    }

    double lsum = lsum0 + lsum1;
#pragma unroll
    for (int off = 32; off > 0; off >>= 1)
        lsum += __shfl_down(lsum, off);

    if (lane == 0) wsum[wid] = lsum;
    __syncthreads();
    if (threadIdx.x == 0) {
        double s = 0.0;
#pragma unroll
        for (int w = 0; w < C_NW; ++w) s += wsum[w];
        atomicAdd(acc, s);
    }
}

// ---------------- fallback (direct gather, f32) ----------------

__device__ __forceinline__ float pair_e_f(float4 ai, float4 aj, const float* P,
                                          float c2, float shift) {
    float dx = ai.x - aj.x, dy = ai.y - aj.y, dz = ai.z - aj.z;
    float sx = dx*P[0] + dy*P[3] + dz*P[6];
    float sy = dx*P[1] + dy*P[4] + dz*P[7];
    float sz = dx*P[2] + dy*P[5] + dz*P[8];
    sx -= floorf(sx + 0.5f);
    sy -= floorf(sy + 0.5f);
    sz -= floorf(sz + 0.5f);
    float px = sx*P[11] + sy*P[14] + sz*P[17];
    float py = sx*P[12] + sy*P[15] + sz*P[18];
    float pz = sx*P[13] + sy*P[16] + sz*P[19];
    px *= 65536.0f; py *= 65536.0f; pz *= 65536.0f;  // par stores box/65536
    float r2 = px*px + py*py + pz*pz;
    float rinv = rsqrtf(r2);
    float e = ai.w * aj.w * (rinv - shift);
    return (r2 <= c2) ? e : 0.0f;
}

__global__ __launch_bounds__(TPB)
void coulomb_direct(const int2* __restrict__ pairs, int npairs,
                    const float* __restrict__ coords,
                    const float* __restrict__ charges,
                    const float* __restrict__ par,
                    double* __restrict__ acc) {
    float P[20];
#pragma unroll
    for (int k = 0; k < 20; ++k) P[k] = par[k];
    double lsum = 0.0;
    int tid = blockIdx.x * blockDim.x + threadIdx.x;
    int stride = gridDim.x * blockDim.x;
    for (int p = tid; p < npairs; p += stride) {
        int2 pr = pairs[p];
        float4 a = make_float4(coords[3*pr.x], coords[3*pr.x+1], coords[3*pr.x+2], charges[pr.x]);
        float4 c = make_float4(coords[3*pr.y], coords[3*pr.y+1], coords[3*pr.y+2], charges[pr.y]);
        lsum += (double)pair_e_f(a, c, P, P[9], P[10]);
    }
#pragma unroll
    for (int off = 32; off > 0; off >>= 1)
        lsum += __shfl_down(lsum, off);
    __shared__ double wsum[TPB / 64];
    int lane = threadIdx.x & 63;
    int wid  = threadIdx.x >> 6;
    if (lane == 0) wsum[wid] = lsum;
    __syncthreads();
    if (threadIdx.x == 0) {
        double s = 0.0;
#pragma unroll
        for (int w = 0; w < TPB / 64; ++w) s += wsum[w];
        atomicAdd(acc, s);
    }
}

__global__ void finalize_kernel(const double* __restrict__ acc,
                                const float* __restrict__ prefac_p,
                                float* __restrict__ out) {
    if (threadIdx.x == 0 && blockIdx.x == 0)
        out[0] = (float)(*acc * (double)(*prefac_p));
}

extern "C" void kernel_launch(void* const* d_in, const int* in_sizes, int n_in,
                              void* d_out, int out_size, void* d_ws, size_t ws_size,
                              hipStream_t stream) {
    const float* coords   = (const float*)d_in[0];
    const int*   pairs    = (const int*)d_in[1];
    const float* box      = (const float*)d_in[2];
    const float* charges  = (const float*)d_in[3];
    const float* prefac   = (const float*)d_in[4];
    const float* cutoff   = (const float*)d_in[5];
    const int*   do_shift = (const int*)d_in[6];
    float* out = (float*)d_out;

    int natoms = in_sizes[0] / 3;
    int npairs = in_sizes[1] / 2;

    double* acc = (double*)d_ws;
    float*  par = (float*)((char*)d_ws + WS_PAR);

    int nchunk  = (natoms + CHUNK - 1) >> CHUNK_SHIFT;
    int nbucket = nchunk * nchunk;
    int nsb     = (npairs + S_PPB - 1) / S_PPB;

    size_t off_table  = WS_TABLE;
    size_t table_b    = (size_t)(nbucket + 1) * nsb * sizeof(unsigned);
    size_t off_qatoms = (off_table + table_b + 255) & ~(size_t)255;
    size_t off_bdata  = (off_qatoms + (size_t)natoms * sizeof(uint2) + 255) & ~(size_t)255;
    size_t need       = off_bdata + (size_t)nsb * S_PPB * sizeof(unsigned);

    bool use_buckets = (nchunk <= NCHUNK_MAX) && (nbucket <= 254) &&
                       (ws_size >= need);

    setup_kernel<<<1, 64, 0, stream>>>(box, cutoff, do_shift, acc, par);

    if (use_buckets) {
        unsigned* tableT = (unsigned*)((char*)d_ws + off_table);
        uint2*    qatoms = (uint2*)((char*)d_ws + off_qatoms);
        unsigned* bdata  = (unsigned*)((char*)d_ws + off_bdata);

        pack_quant_kernel<<<(natoms + TPB - 1) / TPB, TPB, 0, stream>>>(
            coords, charges, par, qatoms, natoms);

        scatter_kernel<<<nsb, S_TPB, 0, stream>>>(
            (const int2*)pairs, npairs, nchunk, nbucket, nsb, tableT, bdata);

        // diag flag is data-dependent but box is fixed per problem; launch both
        // variants is not allowed (determinism is fine — pick via host? box is on
        // device). Launch the generic variant selector: one kernel reads par[20].
        bucket_compute<false><<<nbucket * C_SPLIT, C_TPB, 0, stream>>>(
            bdata, tableT, nsb, qatoms, natoms, nchunk, par, acc);
    } else {
        int blocks = (npairs + TPB - 1) / TPB;
        if (blocks > 2048) blocks = 2048;
        coulomb_direct<<<blocks, TPB, 0, stream>>>(
            (const int2*)pairs, npairs, coords, charges, par, acc);
    }

    finalize_kernel<<<1, 64, 0, stream>>>(acc, prefac, out);
}

// Round 8
// 61.140 us; speedup vs baseline: 1.7368x; 1.0863x over previous
//
#include <hip/hip_runtime.h>
#include <hip/hip_fp16.h>

// Coulomb pair-energy reduction: 2D pair bucketing, atomic-free block-major
// binning + LDS-staged quantized atom tiles (8B: u16 frac coords + f16 charge).
// R7: scatter keys in registers (no LDS round-trip), int4 pair loads, params
// derived per-kernel (no setup kernel), per-block partial sums (no global
// atomics), runtime DIAG fast path, C_SPLIT=4.

constexpr int TPB = 256;

constexpr int CHUNK_SHIFT = 13;
constexpr int CHUNK       = 1 << CHUNK_SHIFT;   // 8192 atoms/chunk
constexpr int NCHUNK_MAX  = 15;
constexpr int NB_MAX      = 256;

constexpr int S_TPB = 512;
constexpr int S_PPT = 16;                       // pairs per thread
constexpr int S_PPB = S_TPB * S_PPT;            // 8192 pairs/block
constexpr int S_I4  = S_PPB / 2;                // 4096 int4 per block
constexpr int S_UI  = S_I4 / S_TPB;             // 8 int4 per thread

constexpr int C_TPB   = 1024;
constexpr int C_SPLIT = 4;
constexpr int C_NW    = C_TPB / 64;

// ws layout (bytes)
constexpr size_t WS_ACC   = 0;      // double (fallback path only)
constexpr size_t WS_PAR   = 16;     // float[21] (fallback path only)
constexpr size_t WS_PARTS = 4096;   // double[<=4096] per-block partials
constexpr size_t WS_TABLE = 4096 + 32768;

// par: [0..8] boxInv, [9] cutoff^2, [10] shift, [11..19] box/65536, [20] diag
__device__ __forceinline__ void compute_par(const float* __restrict__ box,
                                            const float* __restrict__ cutoff_p,
                                            const int* __restrict__ do_shift_p,
                                            float* par) {
    float b00 = box[0], b01 = box[1], b02 = box[2];
    float b10 = box[3], b11 = box[4], b12 = box[5];
    float b20 = box[6], b21 = box[7], b22 = box[8];
    float det = b00*(b11*b22 - b12*b21)
              - b01*(b10*b22 - b12*b20)
              + b02*(b10*b21 - b11*b20);
    float id = 1.0f / det;
    par[0] =  (b11*b22 - b12*b21) * id;
    par[1] = -(b01*b22 - b02*b21) * id;
    par[2] =  (b01*b12 - b02*b11) * id;
    par[3] = -(b10*b22 - b12*b20) * id;
    par[4] =  (b00*b22 - b02*b20) * id;
    par[5] = -(b00*b12 - b02*b10) * id;
    par[6] =  (b10*b21 - b11*b20) * id;
    par[7] = -(b00*b21 - b01*b20) * id;
    par[8] =  (b00*b11 - b01*b10) * id;
    float cut = *cutoff_p;
    par[9]  = cut * cut;
    par[10] = (*do_shift_p) ? (1.0f / cut) : 0.0f;
    constexpr float S = 1.0f / 65536.0f;
    par[11] = b00*S; par[12] = b01*S; par[13] = b02*S;
    par[14] = b10*S; par[15] = b11*S; par[16] = b12*S;
    par[17] = b20*S; par[18] = b21*S; par[19] = b22*S;
    float offd = fabsf(b01) + fabsf(b02) + fabsf(b10)
               + fabsf(b12) + fabsf(b20) + fabsf(b21);
    par[20] = (offd == 0.0f) ? 1.0f : 0.0f;
}

// quantize: s = x @ boxInv, u16 = round(s*65536) mod 65536 (mod-1 wrap exact)
__global__ void pack_quant_kernel(const float* __restrict__ coords,
                                  const float* __restrict__ charges,
                                  const float* __restrict__ box,
                                  const float* __restrict__ cutoff_p,
                                  const int* __restrict__ do_shift_p,
                                  uint2* __restrict__ qatoms, int n) {
    float par[21];
    compute_par(box, cutoff_p, do_shift_p, par);
    int i = blockIdx.x * blockDim.x + threadIdx.x;
    if (i >= n) return;
    float x = coords[3*i], y = coords[3*i+1], z = coords[3*i+2];
    float sx = x*par[0] + y*par[3] + z*par[6];
    float sy = x*par[1] + y*par[4] + z*par[7];
    float sz = x*par[2] + y*par[5] + z*par[8];
    unsigned qx = (unsigned)__float2int_rn(sx * 65536.0f) & 0xFFFFu;
    unsigned qy = (unsigned)__float2int_rn(sy * 65536.0f) & 0xFFFFu;
    unsigned qz = (unsigned)__float2int_rn(sz * 65536.0f) & 0xFFFFu;
    unsigned qc = (unsigned)__half_as_ushort(__float2half(charges[i]));
    qatoms[i] = make_uint2(qx | (qy << 16), qz | (qc << 16));
}

// ---------------- scatter: registers-only staging, atomic-free global ------

__global__ __launch_bounds__(S_TPB)
void scatter_kernel(const int4* __restrict__ pairs4, int npair2, int nchunk,
                    int nbucket, int nsb,
                    unsigned* __restrict__ tableT,   // [nbucket+1][nsb]
                    unsigned* __restrict__ bdata) {
    __shared__ __align__(16) unsigned ordered[S_PPB];   // 32KB
    __shared__ unsigned hist[NB_MAX];
    __shared__ unsigned sA[NB_MAX], sB[NB_MAX];
    __shared__ unsigned cur[NB_MAX];

    int tid = threadIdx.x;
    int blk = blockIdx.x;
    for (int t = tid; t < NB_MAX; t += S_TPB) hist[t] = 0u;
    __syncthreads();

    int base4 = blk * S_I4;
    unsigned k[S_PPT];
    int bb[S_PPT];
#pragma unroll
    for (int u = 0; u < S_UI; ++u) {
        int i4 = base4 + u * S_TPB + tid;
        bool v = (i4 < npair2);
        int4 pp = v ? pairs4[i4] : make_int4(0, 0, 0, 0);
        int u2 = 2 * u;
        if (v) {
            int b0 = (pp.x >> CHUNK_SHIFT) * nchunk + (pp.y >> CHUNK_SHIFT);
            int b1 = (pp.z >> CHUNK_SHIFT) * nchunk + (pp.w >> CHUNK_SHIFT);
            k[u2]     = ((unsigned)(pp.x & (CHUNK-1)) << 16) | (unsigned)(pp.y & (CHUNK-1));
            k[u2 + 1] = ((unsigned)(pp.z & (CHUNK-1)) << 16) | (unsigned)(pp.w & (CHUNK-1));
            bb[u2] = b0; bb[u2 + 1] = b1;
            atomicAdd(&hist[b0], 1u);
            atomicAdd(&hist[b1], 1u);
        } else {
            bb[u2] = -1; bb[u2 + 1] = -1;
        }
    }
    __syncthreads();

    // exclusive scan over NB_MAX (Hillis-Steele, ping-pong)
    unsigned *pa = sA, *pb = sB;
    if (tid < NB_MAX) pa[tid] = hist[tid];
    __syncthreads();
    for (int d = 1; d < NB_MAX; d <<= 1) {
        if (tid < NB_MAX) {
            unsigned v = pa[tid];
            if (tid >= d) v += pa[tid - d];
            pb[tid] = v;
        }
        __syncthreads();
        unsigned* t = pa; pa = pb; pb = t;
    }
    // pa = inclusive scan; write TRANSPOSED table column + init cursors
    if (tid <= nbucket) {
        unsigned excl = (tid == 0) ? 0u : pa[tid - 1];
        tableT[(size_t)tid * nsb + blk] = excl;
        if (tid < nbucket) cur[tid] = excl;
    }
    __syncthreads();

    // LDS scatter into bucket-ordered positions (keys straight from registers)
#pragma unroll
    for (int u = 0; u < S_PPT; ++u) {
        if (bb[u] >= 0) {
            unsigned slot = atomicAdd(&cur[bb[u]], 1u);
            ordered[slot] = k[u];
        }
    }
    __syncthreads();

    // coalesced burst writeout
    unsigned total = pa[nbucket - 1];
    unsigned* dst = bdata + (size_t)blk * S_PPB;
    unsigned n4 = total >> 2;
    const uint4* o4 = (const uint4*)ordered;
    for (unsigned i = tid; i < n4; i += S_TPB)
        ((uint4*)dst)[i] = o4[i];
    for (unsigned i = (n4 << 2) + tid; i < total; i += S_TPB)
        dst[i] = ordered[i];
}

// ---------------- per-bucket compute ----------------

template<bool DIAG>
__device__ __forceinline__ float pair_ener(const uint2* tA, const uint2* tB,
                                           unsigned key, const float* P,
                                           bool valid) {
    uint2 ri = tA[key >> 16];
    uint2 rj = tB[key & 0xFFFFu];
    float dx = (float)(short)(ri.x - rj.x);
    float dy = (float)(short)((ri.x >> 16) - (rj.x >> 16));
    float dz = (float)(short)(ri.y - rj.y);
    float px, py, pz;
    if (DIAG) {
        px = dx * P[11]; py = dy * P[15]; pz = dz * P[19];
    } else {
        px = dx*P[11] + dy*P[14] + dz*P[17];
        py = dx*P[12] + dy*P[15] + dz*P[18];
        pz = dx*P[13] + dy*P[16] + dz*P[19];
    }
    float r2 = px*px + py*py + pz*pz;
    float rinv = rsqrtf(r2);
    float qi = __half2float(__ushort_as_half((unsigned short)(ri.y >> 16)));
    float qj = __half2float(__ushort_as_half((unsigned short)(rj.y >> 16)));
    float e = qi * qj * (rinv - P[10]);
    return (valid && r2 <= P[9]) ? e : 0.0f;
}

template<bool DIAG>
__device__ double walk(const unsigned* __restrict__ bdata,
                       const unsigned* __restrict__ rowB,
                       const unsigned* __restrict__ rowB1,
                       int sA0, int cnt, int lane,
                       const uint2* tA, const uint2* tB, const float* P) {
    double lsum0 = 0.0, lsum1 = 0.0;
    for (int batch = 0; batch < cnt; batch += 64) {
        int bc = min(64, cnt - batch);
        unsigned o0v = 0u, lnv = 0u;
        if (lane < bc) {
            int s = sA0 + batch + lane;
            unsigned a0 = rowB[s];
            unsigned a1 = rowB1[s];
            o0v = a0;
            lnv = a1 - a0;
        }
        for (int kk = 0; kk < bc; kk += 4) {
            unsigned off0 = (unsigned)__shfl((int)o0v, kk);
            unsigned len0 = (kk     < bc) ? (unsigned)__shfl((int)lnv, kk)     : 0u;
            unsigned off1 = (unsigned)__shfl((int)o0v, kk + 1);
            unsigned len1 = (kk + 1 < bc) ? (unsigned)__shfl((int)lnv, kk + 1) : 0u;
            unsigned off2 = (unsigned)__shfl((int)o0v, kk + 2);
            unsigned len2 = (kk + 2 < bc) ? (unsigned)__shfl((int)lnv, kk + 2) : 0u;
            unsigned off3 = (unsigned)__shfl((int)o0v, kk + 3);
            unsigned len3 = (kk + 3 < bc) ? (unsigned)__shfl((int)lnv, kk + 3) : 0u;
            size_t base0 = (size_t)(sA0 + batch + kk    ) * S_PPB + off0;
            size_t base1 = (size_t)(sA0 + batch + kk + 1) * S_PPB + off1;
            size_t base2 = (size_t)(sA0 + batch + kk + 2) * S_PPB + off2;
            size_t base3 = (size_t)(sA0 + batch + kk + 3) * S_PPB + off3;
            unsigned k0 = (lane < (int)len0) ? bdata[base0 + lane] : 0u;
            unsigned k1 = (lane < (int)len1) ? bdata[base1 + lane] : 0u;
            unsigned k2 = (lane < (int)len2) ? bdata[base2 + lane] : 0u;
            unsigned k3 = (lane < (int)len3) ? bdata[base3 + lane] : 0u;
            lsum0 += (double)pair_ener<DIAG>(tA, tB, k0, P, lane < (int)len0);
            lsum1 += (double)pair_ener<DIAG>(tA, tB, k1, P, lane < (int)len1);
            lsum0 += (double)pair_ener<DIAG>(tA, tB, k2, P, lane < (int)len2);
            lsum1 += (double)pair_ener<DIAG>(tA, tB, k3, P, lane < (int)len3);
            if (len0 > 64u) for (unsigned e = 64u + lane; e < len0; e += 64u)
                lsum0 += (double)pair_ener<DIAG>(tA, tB, bdata[base0 + e], P, true);
            if (len1 > 64u) for (unsigned e = 64u + lane; e < len1; e += 64u)
                lsum1 += (double)pair_ener<DIAG>(tA, tB, bdata[base1 + e], P, true);
            if (len2 > 64u) for (unsigned e = 64u + lane; e < len2; e += 64u)
                lsum0 += (double)pair_ener<DIAG>(tA, tB, bdata[base2 + e], P, true);
            if (len3 > 64u) for (unsigned e = 64u + lane; e < len3; e += 64u)
                lsum1 += (double)pair_ener<DIAG>(tA, tB, bdata[base3 + e], P, true);
        }
    }
    return lsum0 + lsum1;
}

__global__ __launch_bounds__(C_TPB)
void bucket_compute(const unsigned* __restrict__ bdata,
                    const unsigned* __restrict__ tableT, int nsb,
                    const uint2* __restrict__ qatoms, int natoms, int nchunk,
                    const float* __restrict__ box,
                    const float* __restrict__ cutoff_p,
                    const int* __restrict__ do_shift_p,
                    double* __restrict__ parts) {
    __shared__ uint2 tA[CHUNK];
    __shared__ uint2 tB[CHUNK];
    __shared__ double wsum[C_NW];
    __shared__ float sP[21];

    if (threadIdx.x == 0) compute_par(box, cutoff_p, do_shift_p, sP);

    int b    = blockIdx.x / C_SPLIT;
    int part = blockIdx.x - b * C_SPLIT;
    int bx = b / nchunk, by = b - bx * nchunk;
    int gx = bx << CHUNK_SHIFT, gy = by << CHUNK_SHIFT;

    for (int t = threadIdx.x; t < CHUNK; t += C_TPB) {
        int ga = gx + t;
        tA[t] = (ga < natoms) ? qatoms[ga] : make_uint2(0u, 0u);
        int gb = gy + t;
        tB[t] = (gb < natoms) ? qatoms[gb] : make_uint2(0u, 0u);
    }
    __syncthreads();

    float P[21];
#pragma unroll
    for (int k = 0; k < 21; ++k) P[k] = sP[k];

    int s0 = (int)(((long long)part * nsb) / C_SPLIT);
    int s1 = (int)(((long long)(part + 1) * nsb) / C_SPLIT);
    int lane = threadIdx.x & 63;
    int wid  = threadIdx.x >> 6;

    int nseg = s1 - s0;
    int spw  = (nseg + C_NW - 1) / C_NW;
    int sA0  = s0 + wid * spw;
    int cnt  = min(spw, s1 - sA0);
    if (cnt < 0) cnt = 0;

    const unsigned* rowB  = tableT + (size_t)b * nsb;
    const unsigned* rowB1 = tableT + (size_t)(b + 1) * nsb;

    double lsum = (P[20] != 0.0f)
        ? walk<true >(bdata, rowB, rowB1, sA0, cnt, lane, tA, tB, P)
        : walk<false>(bdata, rowB, rowB1, sA0, cnt, lane, tA, tB, P);

#pragma unroll
    for (int off = 32; off > 0; off >>= 1)
        lsum += __shfl_down(lsum, off);

    if (lane == 0) wsum[wid] = lsum;
    __syncthreads();
    if (threadIdx.x == 0) {
        double s = 0.0;
#pragma unroll
        for (int w = 0; w < C_NW; ++w) s += wsum[w];
        parts[blockIdx.x] = s;
    }
}

// finalize (bucket path): sum partials + odd-pair tail + prefac
__global__ void finalize_bucket(const double* __restrict__ parts, int n,
                                const float* __restrict__ prefac_p,
                                const float* __restrict__ box,
                                const float* __restrict__ cutoff_p,
                                const int* __restrict__ do_shift_p,
                                const float* __restrict__ coords,
                                const float* __restrict__ charges,
                                const int* __restrict__ pairs, int npairs,
                                float* __restrict__ out) {
    __shared__ double sh[4];
    double s = 0.0;
    for (int i = threadIdx.x; i < n; i += 256) s += parts[i];
#pragma unroll
    for (int off = 32; off > 0; off >>= 1) s += __shfl_down(s, off);
    int lane = threadIdx.x & 63, wid = threadIdx.x >> 6;
    if (lane == 0) sh[wid] = s;
    __syncthreads();
    if (threadIdx.x == 0) {
        double tot = sh[0] + sh[1] + sh[2] + sh[3];
        if (npairs & 1) {
            float par[21];
            compute_par(box, cutoff_p, do_shift_p, par);
            int ii = pairs[2*(npairs-1)], jj = pairs[2*(npairs-1)+1];
            float dx = coords[3*ii]-coords[3*jj];
            float dy = coords[3*ii+1]-coords[3*jj+1];
            float dz = coords[3*ii+2]-coords[3*jj+2];
            float sx = dx*par[0]+dy*par[3]+dz*par[6];
            float sy = dx*par[1]+dy*par[4]+dz*par[7];
            float sz = dx*par[2]+dy*par[5]+dz*par[8];
            sx -= floorf(sx+0.5f); sy -= floorf(sy+0.5f); sz -= floorf(sz+0.5f);
            float px = (sx*par[11]+sy*par[14]+sz*par[17])*65536.0f;
            float py = (sx*par[12]+sy*par[15]+sz*par[18])*65536.0f;
            float pz = (sx*par[13]+sy*par[16]+sz*par[19])*65536.0f;
            float r2 = px*px+py*py+pz*pz;
            float e = charges[ii]*charges[jj]*(rsqrtf(r2)-par[10]);
            if (r2 <= par[9]) tot += (double)e;
        }
        out[0] = (float)(tot * (double)(*prefac_p));
    }
}

// ---------------- fallback (direct gather, f32) ----------------

__global__ void setup_kernel(const float* __restrict__ box,
                             const float* __restrict__ cutoff_p,
                             const int* __restrict__ do_shift_p,
                             double* __restrict__ acc,
                             float* __restrict__ par) {
    if (threadIdx.x == 0 && blockIdx.x == 0) {
        *acc = 0.0;
        compute_par(box, cutoff_p, do_shift_p, par);
    }
}

__device__ __forceinline__ float pair_e_f(float4 ai, float4 aj, const float* P) {
    float dx = ai.x - aj.x, dy = ai.y - aj.y, dz = ai.z - aj.z;
    float sx = dx*P[0] + dy*P[3] + dz*P[6];
    float sy = dx*P[1] + dy*P[4] + dz*P[7];
    float sz = dx*P[2] + dy*P[5] + dz*P[8];
    sx -= floorf(sx + 0.5f);
    sy -= floorf(sy + 0.5f);
    sz -= floorf(sz + 0.5f);
    float px = (sx*P[11] + sy*P[14] + sz*P[17]) * 65536.0f;
    float py = (sx*P[12] + sy*P[15] + sz*P[18]) * 65536.0f;
    float pz = (sx*P[13] + sy*P[16] + sz*P[19]) * 65536.0f;
    float r2 = px*px + py*py + pz*pz;
    float rinv = rsqrtf(r2);
    float e = ai.w * aj.w * (rinv - P[10]);
    return (r2 <= P[9]) ? e : 0.0f;
}

__global__ __launch_bounds__(TPB)
void coulomb_direct(const int2* __restrict__ pairs, int npairs,
                    const float* __restrict__ coords,
                    const float* __restrict__ charges,
                    const float* __restrict__ par,
                    double* __restrict__ acc) {
    float P[21];
#pragma unroll
    for (int k = 0; k < 21; ++k) P[k] = par[k];
    double lsum = 0.0;
    int tid = blockIdx.x * blockDim.x + threadIdx.x;
    int stride = gridDim.x * blockDim.x;
    for (int p = tid; p < npairs; p += stride) {
        int2 pr = pairs[p];
        float4 a = make_float4(coords[3*pr.x], coords[3*pr.x+1], coords[3*pr.x+2], charges[pr.x]);
        float4 c = make_float4(coords[3*pr.y], coords[3*pr.y+1], coords[3*pr.y+2], charges[pr.y]);
        lsum += (double)pair_e_f(a, c, P);
    }
#pragma unroll
    for (int off = 32; off > 0; off >>= 1)
        lsum += __shfl_down(lsum, off);
    __shared__ double wsum[TPB / 64];
    int lane = threadIdx.x & 63;
    int wid  = threadIdx.x >> 6;
    if (lane == 0) wsum[wid] = lsum;
    __syncthreads();
    if (threadIdx.x == 0) {
        double s = 0.0;
#pragma unroll
        for (int w = 0; w < TPB / 64; ++w) s += wsum[w];
        atomicAdd(acc, s);
    }
}

__global__ void finalize_kernel(const double* __restrict__ acc,
                                const float* __restrict__ prefac_p,
                                float* __restrict__ out) {
    if (threadIdx.x == 0 && blockIdx.x == 0)
        out[0] = (float)(*acc * (double)(*prefac_p));
}

extern "C" void kernel_launch(void* const* d_in, const int* in_sizes, int n_in,
                              void* d_out, int out_size, void* d_ws, size_t ws_size,
                              hipStream_t stream) {
    const float* coords   = (const float*)d_in[0];
    const int*   pairs    = (const int*)d_in[1];
    const float* box      = (const float*)d_in[2];
    const float* charges  = (const float*)d_in[3];
    const float* prefac   = (const float*)d_in[4];
    const float* cutoff   = (const float*)d_in[5];
    const int*   do_shift = (const int*)d_in[6];
    float* out = (float*)d_out;

    int natoms = in_sizes[0] / 3;
    int npairs = in_sizes[1] / 2;
    int npair2 = npairs / 2;              // int4 count (even region)
    int npairs_even = npair2 * 2;

    int nchunk  = (natoms + CHUNK - 1) >> CHUNK_SHIFT;
    int nbucket = nchunk * nchunk;
    int nsb     = (npairs_even + S_PPB - 1) / S_PPB;

    size_t off_table  = WS_TABLE;
    size_t table_b    = (size_t)(nbucket + 1) * nsb * sizeof(unsigned);
    size_t off_qatoms = (off_table + table_b + 255) & ~(size_t)255;
    size_t off_bdata  = (off_qatoms + (size_t)natoms * sizeof(uint2) + 255) & ~(size_t)255;
    size_t need       = off_bdata + (size_t)nsb * S_PPB * sizeof(unsigned);

    bool use_buckets = (nchunk <= NCHUNK_MAX) && (nbucket <= NB_MAX - 2) &&
                       (nsb >= 1) && (ws_size >= need) &&
                       (nbucket * C_SPLIT <= 4096);

    if (use_buckets) {
        double*   parts  = (double*)((char*)d_ws + WS_PARTS);
        unsigned* tableT = (unsigned*)((char*)d_ws + off_table);
        uint2*    qatoms = (uint2*)((char*)d_ws + off_qatoms);
        unsigned* bdata  = (unsigned*)((char*)d_ws + off_bdata);

        pack_quant_kernel<<<(natoms + TPB - 1) / TPB, TPB, 0, stream>>>(
            coords, charges, box, cutoff, do_shift, qatoms, natoms);

        scatter_kernel<<<nsb, S_TPB, 0, stream>>>(
            (const int4*)pairs, npair2, nchunk, nbucket, nsb, tableT, bdata);

        int cblocks = nbucket * C_SPLIT;
        bucket_compute<<<cblocks, C_TPB, 0, stream>>>(
            bdata, tableT, nsb, qatoms, natoms, nchunk,
            box, cutoff, do_shift, parts);

        finalize_bucket<<<1, 256, 0, stream>>>(
            parts, cblocks, prefac, box, cutoff, do_shift,
            coords, charges, pairs, npairs, out);
    } else {
        double* acc = (double*)((char*)d_ws + WS_ACC);
        float*  par = (float*)((char*)d_ws + WS_PAR);
        setup_kernel<<<1, 64, 0, stream>>>(box, cutoff, do_shift, acc, par);
        int blocks = (npairs + TPB - 1) / TPB;
        if (blocks > 2048) blocks = 2048;
        coulomb_direct<<<blocks, TPB, 0, stream>>>(
            (const int2*)pairs, npairs, coords, charges, par, acc);
        finalize_kernel<<<1, 64, 0, stream>>>(acc, prefac, out);
    }
}